// Round 1
// baseline (1019.474 us; speedup 1.0000x reference)
//
#include <hip/hip_runtime.h>
#include <math.h>

#define Nn 8192
#define Dd 256
#define Cc 16

// ---- workspace layout (floats) ----
#define OFF_MX   0u          // 8192*256   (MX, later reused as Cnom)
#define OFF_G    2097152u    // 8192*256   (gamma * XW)
#define OFF_G1   4194304u    // 8192       (gamma - 1)
#define OFF_DEN  4202496u    // 8192
#define OFF_RS   4210688u    // 8192
#define OFF_LOG  4218880u    // 8192*16
#define OFF_KC   4349952u    // 64         (per-k consts: p2, pw, an, lam)
#define OFF_PART 4350016u    // 16*8192*16 (j-split partials for final GEMM)
#define WS_FLOATS 6447168u

__device__ __forceinline__ float clip1(float x) {
    return fminf(fmaxf(x, -1.0f + 1e-7f), 1.0f - 1e-7f);
}

__device__ __forceinline__ float waveReduce(float v) {
    #pragma unroll
    for (int off = 32; off; off >>= 1) v += __shfl_down(v, off);
    return v;
}

// 256-thread block sum, result broadcast to all threads
__device__ __forceinline__ float blockReduceBcast(float v, float* red) {
    int t = threadIdx.x, w = t >> 6, l = t & 63;
    v = waveReduce(v);
    if (l == 0) red[w] = v;
    __syncthreads();
    if (t == 0) red[0] = red[0] + red[1] + red[2] + red[3];
    __syncthreads();
    float r = red[0];
    __syncthreads();
    return r;
}

// ---- K0: per-prototype constants ----
__global__ __launch_bounds__(256) void k_consts(const float* __restrict__ Wl,
                                                const float* __restrict__ Pk,
                                                float* __restrict__ kc) {
    __shared__ float red[8];
    int t = threadIdx.x, k = blockIdx.x;
    float pv = Pk[k * Dd + t];
    float wv = Wl[t * Cc + k];
    float p2 = blockReduceBcast(pv * pv, red);
    float pw = blockReduceBcast(pv * wv, red);
    float w2 = blockReduceBcast(wv * wv, red);
    if (t == 0) {
        float an  = fmaxf(sqrtf(w2), 1e-15f);
        float lam = 2.0f / fmaxf(1.0f - p2, 1e-10f);
        kc[k * 4 + 0] = p2; kc[k * 4 + 1] = pw;
        kc[k * 4 + 2] = an; kc[k * 4 + 3] = lam;
    }
}

// ---- K1a: MX = X @ W^T  (8192x256 @ 256x256) ----
__global__ __launch_bounds__(256) void k_xwt(const float* __restrict__ X,
                                             const float* __restrict__ W,
                                             float* __restrict__ MX) {
    __shared__ __align__(16) float Xs[32 * 68];
    __shared__ __align__(16) float Ws[32 * 260];
    int t = threadIdx.x;
    int m0 = blockIdx.x * 64;
    int tx = t & 15, ty = t >> 4;
    float acc[4][16] = {};
    for (int k0 = 0; k0 < Dd; k0 += 32) {
        #pragma unroll
        for (int i = 0; i < 2; ++i) {
            int idx = t + i * 256;
            int row = idx >> 3, kq = idx & 7;
            float4 v = *(const float4*)&X[(size_t)(m0 + row) * Dd + k0 + kq * 4];
            Xs[(kq * 4 + 0) * 68 + row] = v.x;
            Xs[(kq * 4 + 1) * 68 + row] = v.y;
            Xs[(kq * 4 + 2) * 68 + row] = v.z;
            Xs[(kq * 4 + 3) * 68 + row] = v.w;
        }
        #pragma unroll
        for (int i = 0; i < 8; ++i) {
            int n = (t >> 3) + i * 32;
            int kq = t & 7;
            float4 v = *(const float4*)&W[(size_t)n * Dd + k0 + kq * 4];
            Ws[(kq * 4 + 0) * 260 + n] = v.x;
            Ws[(kq * 4 + 1) * 260 + n] = v.y;
            Ws[(kq * 4 + 2) * 260 + n] = v.z;
            Ws[(kq * 4 + 3) * 260 + n] = v.w;
        }
        __syncthreads();
        #pragma unroll
        for (int k = 0; k < 32; ++k) {
            float4 a = *(const float4*)&Xs[k * 68 + ty * 4];
            float av[4] = {a.x, a.y, a.z, a.w};
            #pragma unroll
            for (int q = 0; q < 4; ++q) {
                float4 b = *(const float4*)&Ws[k * 260 + q * 64 + tx * 4];
                float bv[4] = {b.x, b.y, b.z, b.w};
                #pragma unroll
                for (int i2 = 0; i2 < 4; ++i2)
                    #pragma unroll
                    for (int j = 0; j < 4; ++j)
                        acc[i2][q * 4 + j] += av[i2] * bv[j];
            }
        }
        __syncthreads();
    }
    #pragma unroll
    for (int i2 = 0; i2 < 4; ++i2)
        #pragma unroll
        for (int q = 0; q < 4; ++q) {
            float4 v = make_float4(acc[i2][q * 4 + 0], acc[i2][q * 4 + 1],
                                   acc[i2][q * 4 + 2], acc[i2][q * 4 + 3]);
            *(float4*)&MX[(size_t)(m0 + ty * 4 + i2) * Dd + q * 64 + tx * 4] = v;
        }
}

// ---- K1b: per-row mobius_matvec rescale + gamma ----
__global__ __launch_bounds__(256) void k_gamma(const float* __restrict__ X,
                                               const float* __restrict__ MX,
                                               float* __restrict__ G,
                                               float* __restrict__ g1) {
    __shared__ float red[8];
    int i = blockIdx.x, t = threadIdx.x;
    float x  = X[(size_t)i * Dd + t];
    float mx = MX[(size_t)i * Dd + t];
    float xn2  = blockReduceBcast(x * x, red);
    float mxn2 = blockReduceBcast(mx * mx, red);
    float xn  = fmaxf(sqrtf(xn2), 1e-15f);
    float mxn = fmaxf(sqrtf(mxn2), 1e-15f);
    float s = tanhf(mxn / xn * atanhf(clip1(xn))) / mxn;
    float xw = s * mx;
    float xw2 = blockReduceBcast(xw * xw, red);
    float gamma = 2.0f / fmaxf(1.0f - xw2, 1e-10f);
    G[(size_t)i * Dd + t] = gamma * xw;
    if (t == 0) g1[i] = gamma - 1.0f;
}

// ---- K2: Cnom = A @ G ; den = A @ g1 ; rs = A @ 1  (the big GEMM) ----
__global__ __launch_bounds__(256) void k_gemm1(const float* __restrict__ A,
                                               const float* __restrict__ G,
                                               const float* __restrict__ g1,
                                               float* __restrict__ Cnom,
                                               float* __restrict__ den,
                                               float* __restrict__ rs) {
    __shared__ __align__(16) float As[32 * 68];
    __shared__ __align__(16) float Bs[32 * 132];
    __shared__ float g1s[32];
    int t = threadIdx.x;
    int m0 = blockIdx.x * 64;
    int n0 = blockIdx.y * 128;
    int tx = t & 15, ty = t >> 4;
    float acc[4][8] = {};
    float dacc = 0.f, racc = 0.f;
    for (int k0 = 0; k0 < Nn; k0 += 32) {
        #pragma unroll
        for (int i = 0; i < 2; ++i) {
            int idx = t + i * 256;
            int row = idx >> 3, kq = idx & 7;
            float4 v = *(const float4*)&A[(size_t)(m0 + row) * Nn + k0 + kq * 4];
            As[(kq * 4 + 0) * 68 + row] = v.x;
            As[(kq * 4 + 1) * 68 + row] = v.y;
            As[(kq * 4 + 2) * 68 + row] = v.z;
            As[(kq * 4 + 3) * 68 + row] = v.w;
        }
        #pragma unroll
        for (int i = 0; i < 4; ++i) {
            int idx = t + i * 256;
            int krow = idx >> 5, nq = idx & 31;
            *(float4*)&Bs[krow * 132 + nq * 4] =
                *(const float4*)&G[(size_t)(k0 + krow) * Dd + n0 + nq * 4];
        }
        if (blockIdx.y == 0 && t < 32) g1s[t] = g1[k0 + t];
        __syncthreads();
        #pragma unroll
        for (int k = 0; k < 32; ++k) {
            float4 a  = *(const float4*)&As[k * 68 + ty * 4];
            float4 b0 = *(const float4*)&Bs[k * 132 + tx * 4];
            float4 b1 = *(const float4*)&Bs[k * 132 + 64 + tx * 4];
            float av[4] = {a.x, a.y, a.z, a.w};
            float bv[8] = {b0.x, b0.y, b0.z, b0.w, b1.x, b1.y, b1.z, b1.w};
            #pragma unroll
            for (int i2 = 0; i2 < 4; ++i2)
                #pragma unroll
                for (int j = 0; j < 8; ++j)
                    acc[i2][j] += av[i2] * bv[j];
        }
        if (blockIdx.y == 0 && t < 64) {
            #pragma unroll
            for (int k = 0; k < 32; ++k) {
                float av = As[k * 68 + t];
                dacc += av * g1s[k];
                racc += av;
            }
        }
        __syncthreads();
    }
    #pragma unroll
    for (int i2 = 0; i2 < 4; ++i2) {
        size_t base = (size_t)(m0 + ty * 4 + i2) * Dd + n0;
        *(float4*)&Cnom[base + tx * 4] =
            make_float4(acc[i2][0], acc[i2][1], acc[i2][2], acc[i2][3]);
        *(float4*)&Cnom[base + 64 + tx * 4] =
            make_float4(acc[i2][4], acc[i2][5], acc[i2][6], acc[i2][7]);
    }
    if (blockIdx.y == 0 && t < 64) { den[m0 + t] = dacc; rs[m0 + t] = racc; }
}

// ---- K3: per-row gyromidpoint chain + H1 + hyperbolic logits ----
__global__ __launch_bounds__(256) void k_rowfix(const float* __restrict__ Cnom,
                                                const float* __restrict__ den,
                                                const float* __restrict__ rs,
                                                const float* __restrict__ Pk,
                                                const float* __restrict__ Wl,
                                                const float* __restrict__ kc,
                                                float* __restrict__ logits) {
    __shared__ float red[8];
    __shared__ float hs[256];
    __shared__ float PQ[16][2];
    int i = blockIdx.x, t = threadIdx.x;
    float nom = Cnom[(size_t)i * Dd + t];
    float dv = den[i];
    dv = (fabsf(dv) < 1e-10f) ? 1e-10f : dv;
    float tm = nom / dv;                               // two_mean
    float r2 = blockReduceBcast(tm * tm, red);
    float r = fmaxf(sqrtf(r2), 1e-15f);
    float mmul = tanhf(0.5f * atanhf(clip1(r))) / r;   // mobius_scalar_mul(0.5,..)
    float mj = mmul * tm;
    float mn2 = blockReduceBcast(mj * mj, red);
    float mn = fmaxf(sqrtf(mn2), 1e-15f);
    float sA = rs[i];
    float axmul = tanhf(sA * atanhf(clip1(mn))) / mn;  // mobius_scalar_mul(rowsum,..)
    float axw = axmul * mj;
    float yn2 = blockReduceBcast(axw * axw, red);
    float yn = fmaxf(sqrtf(yn2), 1e-15f);
    float v = atanhf(clip1(yn)) / yn * axw;            // logmap0
    float u = fmaxf(v, 0.0f);                          // relu
    float un2 = blockReduceBcast(u * u, red);
    float un = fmaxf(sqrtf(un2), 1e-15f);
    float h = tanhf(un) / un * u;                      // expmap0 -> H1
    float h2 = blockReduceBcast(h * h, red);
    hs[t] = h;
    __syncthreads();
    // 16 prototypes: P_k = h.p_k, Q_k = h.Wl[:,k]; wave w handles k=w*4..w*4+3
    int w = t >> 6, l = t & 63;
    #pragma unroll
    for (int kk = 0; kk < 4; ++kk) {
        int k = w * 4 + kk;
        float pp = 0.f, qq = 0.f;
        #pragma unroll
        for (int m = 0; m < 4; ++m) {
            float hv = hs[l + 64 * m];
            pp += hv * Pk[k * Dd + l + 64 * m];
            qq += hv * Wl[(l + 64 * m) * Cc + k];
        }
        pp = waveReduce(pp);
        qq = waveReduce(qq);
        if (l == 0) { PQ[k][0] = pp; PQ[k][1] = qq; }
    }
    __syncthreads();
    if (t < 16) {
        int k = t;
        float p2 = kc[k * 4 + 0], pw = kc[k * 4 + 1];
        float an = kc[k * 4 + 2], lam = kc[k * 4 + 3];
        float P = PQ[k][0], Q = PQ[k][1];
        // z = mobius_add(-p, h) expanded: z = (alpha*(-p) + beta*h)/Dm
        float alpha = 1.0f - 2.0f * P + h2;
        float beta  = 1.0f - p2;
        float Dm = fmaxf(1.0f - 2.0f * P + p2 * h2, 1e-15f);
        float za  = (-alpha * pw + beta * Q) / Dm;
        float zn2 = (alpha * alpha * p2 - 2.0f * alpha * beta * P + beta * beta * h2)
                    / (Dm * Dm);
        float dd = fmaxf(1.0f - zn2, 1e-10f) * an;
        float dist = asinhf(2.0f * za / dd);
        logits[(size_t)i * Cc + k] = lam * an * dist;
    }
}

// ---- K4: partials of out = A @ logits (j-split x16) ----
__global__ __launch_bounds__(256) void k_gemm2(const float* __restrict__ A,
                                               const float* __restrict__ L,
                                               float* __restrict__ part) {
    __shared__ __align__(16) float Ls[64 * 20];
    __shared__ float Pacc[256 * 16];
    int t = threadIdx.x;
    int r0 = blockIdx.x * 256;
    int jbase = blockIdx.y * 512;
    int q = t & 3, g = t >> 2;
    float acc[4][16] = {};
    for (int jc = 0; jc < 512; jc += 64) {
        {
            int jrow = t >> 2, kq = t & 3;
            *(float4*)&Ls[jrow * 20 + kq * 4] =
                *(const float4*)&L[(size_t)(jbase + jc + jrow) * Cc + kq * 4];
        }
        __syncthreads();
        #pragma unroll
        for (int m = 0; m < 4; ++m) {
            int jl = m * 16 + q * 4;
            float av[4][4];
            #pragma unroll
            for (int rr = 0; rr < 4; ++rr) {
                float4 tmp = *(const float4*)&A[(size_t)(r0 + g * 4 + rr) * Nn
                                                + jbase + jc + jl];
                av[rr][0] = tmp.x; av[rr][1] = tmp.y;
                av[rr][2] = tmp.z; av[rr][3] = tmp.w;
            }
            #pragma unroll
            for (int jj = 0; jj < 4; ++jj) {
                const float* lr = &Ls[(jl + jj) * 20];
                float lv[16];
                #pragma unroll
                for (int k2 = 0; k2 < 16; k2 += 4) {
                    float4 lt = *(const float4*)&lr[k2];
                    lv[k2] = lt.x; lv[k2 + 1] = lt.y;
                    lv[k2 + 2] = lt.z; lv[k2 + 3] = lt.w;
                }
                #pragma unroll
                for (int rr = 0; rr < 4; ++rr)
                    #pragma unroll
                    for (int k2 = 0; k2 < 16; ++k2)
                        acc[rr][k2] += av[rr][jj] * lv[k2];
            }
        }
        __syncthreads();
    }
    for (int ii = t; ii < 4096; ii += 256) Pacc[ii] = 0.f;
    __syncthreads();
    for (int qq = 0; qq < 4; ++qq) {
        if (q == qq) {
            #pragma unroll
            for (int rr = 0; rr < 4; ++rr)
                #pragma unroll
                for (int k2 = 0; k2 < 16; ++k2)
                    Pacc[(g * 4 + rr) * 16 + k2] += acc[rr][k2];
        }
        __syncthreads();
    }
    float* dst = &part[(size_t)blockIdx.y * (Nn * Cc) + (size_t)r0 * Cc];
    for (int ii = t * 4; ii < 4096; ii += 1024)
        *(float4*)&dst[ii] = *(const float4*)&Pacc[ii];
}

// ---- K5: reduce j-split partials ----
__global__ __launch_bounds__(256) void k_reduce(const float* __restrict__ part,
                                                float* __restrict__ out) {
    int i = blockIdx.x * 256 + threadIdx.x;
    float s = 0.f;
    #pragma unroll
    for (int j = 0; j < 16; ++j) s += part[(size_t)j * (Nn * Cc) + i];
    out[i] = s;
}

extern "C" void kernel_launch(void* const* d_in, const int* in_sizes, int n_in,
                              void* d_out, int out_size, void* d_ws, size_t ws_size,
                              hipStream_t stream) {
    const float* X  = (const float*)d_in[0];
    const float* A  = (const float*)d_in[1];
    const float* W  = (const float*)d_in[2];
    const float* Wl = (const float*)d_in[3];
    const float* Pk = (const float*)d_in[4];
    float* out = (float*)d_out;
    float* ws = (float*)d_ws;
    if (ws_size < (size_t)WS_FLOATS * sizeof(float)) return;

    float* MX   = ws + OFF_MX;   // later reused as Cnom
    float* G    = ws + OFF_G;
    float* g1   = ws + OFF_G1;
    float* den  = ws + OFF_DEN;
    float* rsum = ws + OFF_RS;
    float* lg   = ws + OFF_LOG;
    float* kc   = ws + OFF_KC;
    float* part = ws + OFF_PART;

    k_consts<<<16, 256, 0, stream>>>(Wl, Pk, kc);
    k_xwt<<<128, 256, 0, stream>>>(X, W, MX);
    k_gamma<<<Nn, 256, 0, stream>>>(X, MX, G, g1);
    k_gemm1<<<dim3(128, 2), 256, 0, stream>>>(A, G, g1, MX /*Cnom*/, den, rsum);
    k_rowfix<<<Nn, 256, 0, stream>>>(MX /*Cnom*/, den, rsum, Pk, Wl, kc, lg);
    k_gemm2<<<dim3(32, 16), 256, 0, stream>>>(A, lg, part);
    k_reduce<<<512, 256, 0, stream>>>(part, out);
}

// Round 2
// 511.129 us; speedup vs baseline: 1.9946x; 1.9946x over previous
//
#include <hip/hip_runtime.h>
#include <math.h>

#define Nn 8192
#define Dd 256
#define Cc 16

// ---- workspace layout (floats) ----
#define OFF_P0   0u          // 8192*256: MX -> gemm1 partial0 -> gemm2 partials
#define OFF_P1   2097152u    // 8192*256: gemm1 partial1
#define OFF_G    4194304u    // bf16[8192*256] = 1048576 floats; later logits f32
#define OFF_GT   5242880u    // bf16[256*8192] transposed
#define OFF_G1   6291456u    // 8192 f32
#define OFF_DEN  6299648u    // 2*8192 (split partials)
#define OFF_RS   6316032u    // 2*8192
#define OFF_KC   6332416u    // 64
#define WS_FLOATS 6332480u

typedef short vshort8 __attribute__((ext_vector_type(8)));
typedef float vfloat4 __attribute__((ext_vector_type(4)));

__device__ __forceinline__ float clip1(float x) {
    return fminf(fmaxf(x, -1.0f + 1e-7f), 1.0f - 1e-7f);
}

__device__ __forceinline__ unsigned short f2bf(float f) {
    unsigned int u = __float_as_uint(f);
    u += 0x7fff + ((u >> 16) & 1);          // round-to-nearest-even
    return (unsigned short)(u >> 16);
}

__device__ __forceinline__ float waveReduce(float v) {
    #pragma unroll
    for (int off = 32; off; off >>= 1) v += __shfl_down(v, off);
    return v;
}

__device__ __forceinline__ float blockReduceBcast(float v, float* red) {
    int t = threadIdx.x, w = t >> 6, l = t & 63;
    v = waveReduce(v);
    if (l == 0) red[w] = v;
    __syncthreads();
    if (t == 0) red[0] = red[0] + red[1] + red[2] + red[3];
    __syncthreads();
    float r = red[0];
    __syncthreads();
    return r;
}

// ---- K0: per-prototype constants ----
__global__ __launch_bounds__(256) void k_consts(const float* __restrict__ Wl,
                                                const float* __restrict__ Pk,
                                                float* __restrict__ kc) {
    __shared__ float red[8];
    int t = threadIdx.x, k = blockIdx.x;
    float pv = Pk[k * Dd + t];
    float wv = Wl[t * Cc + k];
    float p2 = blockReduceBcast(pv * pv, red);
    float pw = blockReduceBcast(pv * wv, red);
    float w2 = blockReduceBcast(wv * wv, red);
    if (t == 0) {
        float an  = fmaxf(sqrtf(w2), 1e-15f);
        float lam = 2.0f / fmaxf(1.0f - p2, 1e-10f);
        kc[k * 4 + 0] = p2; kc[k * 4 + 1] = pw;
        kc[k * 4 + 2] = an; kc[k * 4 + 3] = lam;
    }
}

// ---- K1a: MX = X @ W^T (fp32 VALU; 1 GFLOP, small) ----
__global__ __launch_bounds__(256) void k_xwt(const float* __restrict__ X,
                                             const float* __restrict__ W,
                                             float* __restrict__ MX) {
    __shared__ __align__(16) float Xs[32 * 68];
    __shared__ __align__(16) float Ws[32 * 260];
    int t = threadIdx.x;
    int m0 = blockIdx.x * 64;
    int tx = t & 15, ty = t >> 4;
    float acc[4][16] = {};
    for (int k0 = 0; k0 < Dd; k0 += 32) {
        #pragma unroll
        for (int i = 0; i < 2; ++i) {
            int idx = t + i * 256;
            int row = idx >> 3, kq = idx & 7;
            float4 v = *(const float4*)&X[(size_t)(m0 + row) * Dd + k0 + kq * 4];
            Xs[(kq * 4 + 0) * 68 + row] = v.x;
            Xs[(kq * 4 + 1) * 68 + row] = v.y;
            Xs[(kq * 4 + 2) * 68 + row] = v.z;
            Xs[(kq * 4 + 3) * 68 + row] = v.w;
        }
        #pragma unroll
        for (int i = 0; i < 8; ++i) {
            int n = (t >> 3) + i * 32;
            int kq = t & 7;
            float4 v = *(const float4*)&W[(size_t)n * Dd + k0 + kq * 4];
            Ws[(kq * 4 + 0) * 260 + n] = v.x;
            Ws[(kq * 4 + 1) * 260 + n] = v.y;
            Ws[(kq * 4 + 2) * 260 + n] = v.z;
            Ws[(kq * 4 + 3) * 260 + n] = v.w;
        }
        __syncthreads();
        #pragma unroll
        for (int k = 0; k < 32; ++k) {
            float4 a = *(const float4*)&Xs[k * 68 + ty * 4];
            float av[4] = {a.x, a.y, a.z, a.w};
            #pragma unroll
            for (int q = 0; q < 4; ++q) {
                float4 b = *(const float4*)&Ws[k * 260 + q * 64 + tx * 4];
                float bv[4] = {b.x, b.y, b.z, b.w};
                #pragma unroll
                for (int i2 = 0; i2 < 4; ++i2)
                    #pragma unroll
                    for (int j = 0; j < 4; ++j)
                        acc[i2][q * 4 + j] += av[i2] * bv[j];
            }
        }
        __syncthreads();
    }
    #pragma unroll
    for (int i2 = 0; i2 < 4; ++i2)
        #pragma unroll
        for (int q = 0; q < 4; ++q) {
            float4 v = make_float4(acc[i2][q * 4 + 0], acc[i2][q * 4 + 1],
                                   acc[i2][q * 4 + 2], acc[i2][q * 4 + 3]);
            *(float4*)&MX[(size_t)(m0 + ty * 4 + i2) * Dd + q * 64 + tx * 4] = v;
        }
}

// ---- K1b: per-row mobius_matvec rescale + gamma; writes G in bf16 ----
__global__ __launch_bounds__(256) void k_gamma(const float* __restrict__ X,
                                               const float* __restrict__ MX,
                                               unsigned short* __restrict__ G,
                                               float* __restrict__ g1) {
    __shared__ float red[8];
    int i = blockIdx.x, t = threadIdx.x;
    float x  = X[(size_t)i * Dd + t];
    float mx = MX[(size_t)i * Dd + t];
    float xn2  = blockReduceBcast(x * x, red);
    float mxn2 = blockReduceBcast(mx * mx, red);
    float xn  = fmaxf(sqrtf(xn2), 1e-15f);
    float mxn = fmaxf(sqrtf(mxn2), 1e-15f);
    float s = tanhf(mxn / xn * atanhf(clip1(xn))) / mxn;
    float xw = s * mx;
    float xw2 = blockReduceBcast(xw * xw, red);
    float gamma = 2.0f / fmaxf(1.0f - xw2, 1e-10f);
    G[(size_t)i * Dd + t] = f2bf(gamma * xw);
    if (t == 0) g1[i] = gamma - 1.0f;
}

// ---- K1c: Gt = transpose(G)  (bf16, 64x64 LDS tiles) ----
__global__ __launch_bounds__(256) void k_tr(const unsigned short* __restrict__ G,
                                            unsigned short* __restrict__ Gt) {
    __shared__ unsigned short Ts[64 * 66];
    int t = threadIdx.x;
    int i0 = blockIdx.x * 64;   // row block in G
    int j0 = blockIdx.y * 64;   // col block in G
    {
        int r = t >> 2, cq = t & 3;
        const uint4* src = (const uint4*)&G[(size_t)(i0 + r) * Dd + j0 + cq * 16];
        uint4 v0 = src[0], v1 = src[1];
        *(uint4*)&Ts[r * 66 + cq * 16]     = v0;
        *(uint4*)&Ts[r * 66 + cq * 16 + 8] = v1;
    }
    __syncthreads();
    {
        int c = t >> 2, rq = t & 3;
        unsigned short v[16];
        #pragma unroll
        for (int e = 0; e < 16; ++e) v[e] = Ts[(rq * 16 + e) * 66 + c];
        uint4 o0, o1;
        unsigned int* o = (unsigned int*)&o0;
        #pragma unroll
        for (int q = 0; q < 4; ++q)
            o[q] = (unsigned int)v[q * 2] | ((unsigned int)v[q * 2 + 1] << 16);
        o = (unsigned int*)&o1;
        #pragma unroll
        for (int q = 0; q < 4; ++q)
            o[q] = (unsigned int)v[8 + q * 2] | ((unsigned int)v[8 + q * 2 + 1] << 16);
        uint4* dst = (uint4*)&Gt[(size_t)(j0 + c) * Nn + i0 + rq * 16];
        dst[0] = o0; dst[1] = o1;
    }
}

// ---- K2: MFMA bf16 GEMM: P[split] = A(k-slice) @ G ; den/rs folded in staging ----
// BM=32, BN=256 (full N -> A read once), BK=64, split-K=2, 512 blocks, 4 waves.
__global__ __launch_bounds__(256, 2) void k_gemm1_mfma(const float* __restrict__ A,
                                                       const unsigned short* __restrict__ Gt,
                                                       const float* __restrict__ g1,
                                                       float* __restrict__ Ppart,
                                                       float* __restrict__ denp,
                                                       float* __restrict__ rsp) {
    __shared__ __align__(16) unsigned short As[32 * 64];
    __shared__ __align__(16) unsigned short Bs[256 * 64];
    int t = threadIdx.x;
    int l = t & 63, w = t >> 6;
    // bijective XCD swizzle: XCD x gets 64 contiguous (split,mtile) blocks
    int id = blockIdx.x;
    int swz = (id & 7) * 64 + (id >> 3);
    int splt = swz >> 8;          // 0..1
    int mtile = swz & 255;        // 0..255
    int m0 = mtile * 32;
    int kb = splt * 4096;

    int ar = t >> 3, aq = t & 7;  // A staging: row 0..31, k-chunk 0..7 (8 fp32)
    int c0 = w * 64;              // wave's 64 output cols

    vfloat4 acc[2][4];
    #pragma unroll
    for (int mi = 0; mi < 2; ++mi)
        #pragma unroll
        for (int ni = 0; ni < 4; ++ni)
            acc[mi][ni] = (vfloat4){0.f, 0.f, 0.f, 0.f};

    float dacc = 0.f, racc = 0.f;
    float4 a0, a1;
    uint4 br[8];

    // ---- stage-load tile 0 into regs ----
    {
        const float* Ap = &A[(size_t)(m0 + ar) * Nn + kb + aq * 8];
        a0 = *(const float4*)Ap;
        a1 = *(const float4*)(Ap + 4);
        #pragma unroll
        for (int i = 0; i < 8; ++i) {
            int ci = i * 256 + t;
            int col = ci >> 3, j = ci & 7;
            br[i] = *(const uint4*)&Gt[(size_t)col * Nn + kb + j * 8];
        }
    }
    // ---- write tile 0 + den accum ----
    {
        float av[8] = {a0.x, a0.y, a0.z, a0.w, a1.x, a1.y, a1.z, a1.w};
        vshort8 ab;
        #pragma unroll
        for (int e = 0; e < 8; ++e) {
            ab[e] = (short)f2bf(av[e]);
            dacc += av[e] * g1[kb + aq * 8 + e];
            racc += av[e];
        }
        *(vshort8*)&As[ar * 64 + ((aq * 8) ^ ((ar & 7) << 3))] = ab;
        #pragma unroll
        for (int i = 0; i < 8; ++i) {
            int ci = i * 256 + t;
            int col = ci >> 3, j = ci & 7;
            *(uint4*)&Bs[col * 64 + ((j * 8) ^ ((col & 7) << 3))] = br[i];
        }
    }
    __syncthreads();

    for (int kt = 0; kt < 64; ++kt) {
        bool more = (kt + 1 < 64);
        int knext = kb + (kt + 1) * 64;
        if (more) {
            const float* Ap = &A[(size_t)(m0 + ar) * Nn + knext + aq * 8];
            a0 = *(const float4*)Ap;
            a1 = *(const float4*)(Ap + 4);
            #pragma unroll
            for (int i = 0; i < 8; ++i) {
                int ci = i * 256 + t;
                int col = ci >> 3, j = ci & 7;
                br[i] = *(const uint4*)&Gt[(size_t)col * Nn + knext + j * 8];
            }
        }
        // ---- compute current tile from LDS ----
        #pragma unroll
        for (int kk = 0; kk < 64; kk += 32) {
            vshort8 af[2], bfr[4];
            int kidx = kk + (l >> 4) * 8;
            #pragma unroll
            for (int mi = 0; mi < 2; ++mi) {
                int row = mi * 16 + (l & 15);
                af[mi] = *(const vshort8*)&As[row * 64 + (kidx ^ ((row & 7) << 3))];
            }
            #pragma unroll
            for (int ni = 0; ni < 4; ++ni) {
                int col = c0 + ni * 16 + (l & 15);
                bfr[ni] = *(const vshort8*)&Bs[col * 64 + (kidx ^ ((col & 7) << 3))];
            }
            #pragma unroll
            for (int mi = 0; mi < 2; ++mi)
                #pragma unroll
                for (int ni = 0; ni < 4; ++ni)
                    acc[mi][ni] = __builtin_amdgcn_mfma_f32_16x16x32_bf16(
                        af[mi], bfr[ni], acc[mi][ni], 0, 0, 0);
        }
        __syncthreads();
        if (more) {
            float av[8] = {a0.x, a0.y, a0.z, a0.w, a1.x, a1.y, a1.z, a1.w};
            vshort8 ab;
            #pragma unroll
            for (int e = 0; e < 8; ++e) {
                ab[e] = (short)f2bf(av[e]);
                dacc += av[e] * g1[knext + aq * 8 + e];
                racc += av[e];
            }
            *(vshort8*)&As[ar * 64 + ((aq * 8) ^ ((ar & 7) << 3))] = ab;
            #pragma unroll
            for (int i = 0; i < 8; ++i) {
                int ci = i * 256 + t;
                int col = ci >> 3, j = ci & 7;
                *(uint4*)&Bs[col * 64 + ((j * 8) ^ ((col & 7) << 3))] = br[i];
            }
        }
        __syncthreads();
    }

    // ---- den/rs: reduce across the 8 k-chunk threads of each row ----
    dacc += __shfl_xor(dacc, 1); dacc += __shfl_xor(dacc, 2); dacc += __shfl_xor(dacc, 4);
    racc += __shfl_xor(racc, 1); racc += __shfl_xor(racc, 2); racc += __shfl_xor(racc, 4);
    if (aq == 0 && w == (ar >> 3)) {  // one writer per row (w owning that ar range)
        denp[splt * Nn + m0 + ar] = dacc;
        rsp[splt * Nn + m0 + ar] = racc;
    }

    // ---- store fp32 partial ----
    float* P = Ppart + (size_t)splt * ((size_t)Nn * Dd);
    #pragma unroll
    for (int mi = 0; mi < 2; ++mi)
        #pragma unroll
        for (int ni = 0; ni < 4; ++ni) {
            int row = m0 + mi * 16 + ((l >> 4) << 2);
            int col = c0 + ni * 16 + (l & 15);
            #pragma unroll
            for (int j = 0; j < 4; ++j)
                P[(size_t)(row + j) * Dd + col] = acc[mi][ni][j];
        }
}

// ---- K3: per-row gyromidpoint chain + H1 + hyperbolic logits ----
__global__ __launch_bounds__(256) void k_rowfix(const float* __restrict__ P0,
                                                const float* __restrict__ P1,
                                                const float* __restrict__ denp,
                                                const float* __restrict__ rsp,
                                                const float* __restrict__ Pk,
                                                const float* __restrict__ Wl,
                                                const float* __restrict__ kc,
                                                float* __restrict__ logits) {
    __shared__ float red[8];
    __shared__ float hs[256];
    __shared__ float PQ[16][2];
    int i = blockIdx.x, t = threadIdx.x;
    float nom = P0[(size_t)i * Dd + t] + P1[(size_t)i * Dd + t];
    float dv = denp[i] + denp[Nn + i];
    dv = (fabsf(dv) < 1e-10f) ? 1e-10f : dv;
    float tm = nom / dv;
    float r2 = blockReduceBcast(tm * tm, red);
    float r = fmaxf(sqrtf(r2), 1e-15f);
    float mmul = tanhf(0.5f * atanhf(clip1(r))) / r;
    float mj = mmul * tm;
    float mn2 = blockReduceBcast(mj * mj, red);
    float mn = fmaxf(sqrtf(mn2), 1e-15f);
    float sA = rsp[i] + rsp[Nn + i];
    float axmul = tanhf(sA * atanhf(clip1(mn))) / mn;
    float axw = axmul * mj;
    float yn2 = blockReduceBcast(axw * axw, red);
    float yn = fmaxf(sqrtf(yn2), 1e-15f);
    float v = atanhf(clip1(yn)) / yn * axw;
    float u = fmaxf(v, 0.0f);
    float un2 = blockReduceBcast(u * u, red);
    float un = fmaxf(sqrtf(un2), 1e-15f);
    float h = tanhf(un) / un * u;
    float h2 = blockReduceBcast(h * h, red);
    hs[t] = h;
    __syncthreads();
    int w = t >> 6, l = t & 63;
    #pragma unroll
    for (int kk = 0; kk < 4; ++kk) {
        int k = w * 4 + kk;
        float pp = 0.f, qq = 0.f;
        #pragma unroll
        for (int m = 0; m < 4; ++m) {
            float hv = hs[l + 64 * m];
            pp += hv * Pk[k * Dd + l + 64 * m];
            qq += hv * Wl[(l + 64 * m) * Cc + k];
        }
        pp = waveReduce(pp);
        qq = waveReduce(qq);
        if (l == 0) { PQ[k][0] = pp; PQ[k][1] = qq; }
    }
    __syncthreads();
    if (t < 16) {
        int k = t;
        float p2 = kc[k * 4 + 0], pw = kc[k * 4 + 1];
        float an = kc[k * 4 + 2], lam = kc[k * 4 + 3];
        float P = PQ[k][0], Q = PQ[k][1];
        float alpha = 1.0f - 2.0f * P + h2;
        float beta  = 1.0f - p2;
        float Dm = fmaxf(1.0f - 2.0f * P + p2 * h2, 1e-15f);
        float za  = (-alpha * pw + beta * Q) / Dm;
        float zn2 = (alpha * alpha * p2 - 2.0f * alpha * beta * P + beta * beta * h2)
                    / (Dm * Dm);
        float dd = fmaxf(1.0f - zn2, 1e-10f) * an;
        float dist = asinhf(2.0f * za / dd);
        logits[(size_t)i * Cc + k] = lam * an * dist;
    }
}

// ---- K4: partials of out = A @ logits (j-split x16) ----
__global__ __launch_bounds__(256) void k_gemm2(const float* __restrict__ A,
                                               const float* __restrict__ L,
                                               float* __restrict__ part) {
    __shared__ __align__(16) float Ls[64 * 20];
    __shared__ float Pacc[256 * 16];
    int t = threadIdx.x;
    int r0 = blockIdx.x * 256;
    int jbase = blockIdx.y * 512;
    int q = t & 3, g = t >> 2;
    float acc[4][16] = {};
    for (int jc = 0; jc < 512; jc += 64) {
        {
            int jrow = t >> 2, kq = t & 3;
            *(float4*)&Ls[jrow * 20 + kq * 4] =
                *(const float4*)&L[(size_t)(jbase + jc + jrow) * Cc + kq * 4];
        }
        __syncthreads();
        #pragma unroll
        for (int m = 0; m < 4; ++m) {
            int jl = m * 16 + q * 4;
            float av[4][4];
            #pragma unroll
            for (int rr = 0; rr < 4; ++rr) {
                float4 tmp = *(const float4*)&A[(size_t)(r0 + g * 4 + rr) * Nn
                                                + jbase + jc + jl];
                av[rr][0] = tmp.x; av[rr][1] = tmp.y;
                av[rr][2] = tmp.z; av[rr][3] = tmp.w;
            }
            #pragma unroll
            for (int jj = 0; jj < 4; ++jj) {
                const float* lr = &Ls[(jl + jj) * 20];
                float lv[16];
                #pragma unroll
                for (int k2 = 0; k2 < 16; k2 += 4) {
                    float4 lt = *(const float4*)&lr[k2];
                    lv[k2] = lt.x; lv[k2 + 1] = lt.y;
                    lv[k2 + 2] = lt.z; lv[k2 + 3] = lt.w;
                }
                #pragma unroll
                for (int rr = 0; rr < 4; ++rr)
                    #pragma unroll
                    for (int k2 = 0; k2 < 16; ++k2)
                        acc[rr][k2] += av[rr][jj] * lv[k2];
            }
        }
        __syncthreads();
    }
    for (int ii = t; ii < 4096; ii += 256) Pacc[ii] = 0.f;
    __syncthreads();
    for (int qq = 0; qq < 4; ++qq) {
        if (q == qq) {
            #pragma unroll
            for (int rr = 0; rr < 4; ++rr)
                #pragma unroll
                for (int k2 = 0; k2 < 16; ++k2)
                    Pacc[(g * 4 + rr) * 16 + k2] += acc[rr][k2];
        }
        __syncthreads();
    }
    float* dst = &part[(size_t)blockIdx.y * (Nn * Cc) + (size_t)r0 * Cc];
    for (int ii = t * 4; ii < 4096; ii += 1024)
        *(float4*)&dst[ii] = *(const float4*)&Pacc[ii];
}

// ---- K5: reduce j-split partials ----
__global__ __launch_bounds__(256) void k_reduce(const float* __restrict__ part,
                                                float* __restrict__ out) {
    int i = blockIdx.x * 256 + threadIdx.x;
    float s = 0.f;
    #pragma unroll
    for (int j = 0; j < 16; ++j) s += part[(size_t)j * (Nn * Cc) + i];
    out[i] = s;
}

extern "C" void kernel_launch(void* const* d_in, const int* in_sizes, int n_in,
                              void* d_out, int out_size, void* d_ws, size_t ws_size,
                              hipStream_t stream) {
    const float* X  = (const float*)d_in[0];
    const float* A  = (const float*)d_in[1];
    const float* W  = (const float*)d_in[2];
    const float* Wl = (const float*)d_in[3];
    const float* Pk = (const float*)d_in[4];
    float* out = (float*)d_out;
    float* ws = (float*)d_ws;
    if (ws_size < (size_t)WS_FLOATS * sizeof(float)) return;

    float* P0 = ws + OFF_P0;                       // MX -> partial0 -> gemm2 part
    float* P1 = ws + OFF_P1;
    unsigned short* G  = (unsigned short*)(ws + OFF_G);
    unsigned short* Gt = (unsigned short*)(ws + OFF_GT);
    float* lg   = ws + OFF_G;                      // logits reuse G region
    float* g1   = ws + OFF_G1;
    float* denp = ws + OFF_DEN;
    float* rsp  = ws + OFF_RS;
    float* kc   = ws + OFF_KC;

    k_consts<<<16, 256, 0, stream>>>(Wl, Pk, kc);
    k_xwt<<<128, 256, 0, stream>>>(X, W, P0 /*MX*/);
    k_gamma<<<Nn, 256, 0, stream>>>(X, P0 /*MX*/, G, g1);
    k_tr<<<dim3(128, 4), 256, 0, stream>>>(G, Gt);
    k_gemm1_mfma<<<512, 256, 0, stream>>>(A, Gt, g1, P0, denp, rsp);
    k_rowfix<<<Nn, 256, 0, stream>>>(P0, P1, denp, rsp, Pk, Wl, kc, lg);
    k_gemm2<<<dim3(32, 16), 256, 0, stream>>>(A, lg, P0);
    k_reduce<<<512, 256, 0, stream>>>(P0, out);
}

// Round 3
// 277.771 us; speedup vs baseline: 3.6702x; 1.8401x over previous
//
#include <hip/hip_runtime.h>
#include <math.h>

#define Nn 8192
#define Dd 256
#define Cc 16

// ---- workspace layout (floats) ----
#define OFF_P0   0u          // 8192*256: MX -> gemm1 partial0 -> gemm2 partials
#define OFF_P1   2097152u    // 8192*256: gemm1 partial1
#define OFF_G    4194304u    // bf16[8192*256]; later logits f32 (131072 floats)
#define OFF_GT   5242880u    // bf16[256*8192] transposed
#define OFF_G1B  6291456u    // bf16[8192] (gamma-1)
#define OFF_DEN  6295552u    // 2*8192 f32 (split partials)
#define OFF_RS   6311936u    // 2*8192 f32
#define OFF_KC   6328320u    // 64
#define WS_FLOATS 6328384u

typedef short vshort8 __attribute__((ext_vector_type(8)));
typedef float vfloat4 __attribute__((ext_vector_type(4)));

#define AS1 __attribute__((address_space(1)))
#define AS3 __attribute__((address_space(3)))

__device__ __forceinline__ float clip1(float x) {
    return fminf(fmaxf(x, -1.0f + 1e-7f), 1.0f - 1e-7f);
}

__device__ __forceinline__ unsigned short f2bf(float f) {
    unsigned int u = __float_as_uint(f);
    u += 0x7fff + ((u >> 16) & 1);          // round-to-nearest-even
    return (unsigned short)(u >> 16);
}

__device__ __forceinline__ float waveReduce(float v) {
    #pragma unroll
    for (int off = 32; off; off >>= 1) v += __shfl_down(v, off);
    return v;
}

__device__ __forceinline__ float blockReduceBcast(float v, float* red) {
    int t = threadIdx.x, w = t >> 6, l = t & 63;
    v = waveReduce(v);
    if (l == 0) red[w] = v;
    __syncthreads();
    if (t == 0) red[0] = red[0] + red[1] + red[2] + red[3];
    __syncthreads();
    float r = red[0];
    __syncthreads();
    return r;
}

// ---- K0: per-prototype constants ----
__global__ __launch_bounds__(256) void k_consts(const float* __restrict__ Wl,
                                                const float* __restrict__ Pk,
                                                float* __restrict__ kc) {
    __shared__ float red[8];
    int t = threadIdx.x, k = blockIdx.x;
    float pv = Pk[k * Dd + t];
    float wv = Wl[t * Cc + k];
    float p2 = blockReduceBcast(pv * pv, red);
    float pw = blockReduceBcast(pv * wv, red);
    float w2 = blockReduceBcast(wv * wv, red);
    if (t == 0) {
        float an  = fmaxf(sqrtf(w2), 1e-15f);
        float lam = 2.0f / fmaxf(1.0f - p2, 1e-10f);
        kc[k * 4 + 0] = p2; kc[k * 4 + 1] = pw;
        kc[k * 4 + 2] = an; kc[k * 4 + 3] = lam;
    }
}

// ---- K1a: MX = X @ W^T (fp32 VALU; small) ----
__global__ __launch_bounds__(256) void k_xwt(const float* __restrict__ X,
                                             const float* __restrict__ W,
                                             float* __restrict__ MX) {
    __shared__ __align__(16) float Xs[32 * 68];
    __shared__ __align__(16) float Ws[32 * 260];
    int t = threadIdx.x;
    int m0 = blockIdx.x * 64;
    int tx = t & 15, ty = t >> 4;
    float acc[4][16] = {};
    for (int k0 = 0; k0 < Dd; k0 += 32) {
        #pragma unroll
        for (int i = 0; i < 2; ++i) {
            int idx = t + i * 256;
            int row = idx >> 3, kq = idx & 7;
            float4 v = *(const float4*)&X[(size_t)(m0 + row) * Dd + k0 + kq * 4];
            Xs[(kq * 4 + 0) * 68 + row] = v.x;
            Xs[(kq * 4 + 1) * 68 + row] = v.y;
            Xs[(kq * 4 + 2) * 68 + row] = v.z;
            Xs[(kq * 4 + 3) * 68 + row] = v.w;
        }
        #pragma unroll
        for (int i = 0; i < 8; ++i) {
            int n = (t >> 3) + i * 32;
            int kq = t & 7;
            float4 v = *(const float4*)&W[(size_t)n * Dd + k0 + kq * 4];
            Ws[(kq * 4 + 0) * 260 + n] = v.x;
            Ws[(kq * 4 + 1) * 260 + n] = v.y;
            Ws[(kq * 4 + 2) * 260 + n] = v.z;
            Ws[(kq * 4 + 3) * 260 + n] = v.w;
        }
        __syncthreads();
        #pragma unroll
        for (int k = 0; k < 32; ++k) {
            float4 a = *(const float4*)&Xs[k * 68 + ty * 4];
            float av[4] = {a.x, a.y, a.z, a.w};
            #pragma unroll
            for (int q = 0; q < 4; ++q) {
                float4 b = *(const float4*)&Ws[k * 260 + q * 64 + tx * 4];
                float bv[4] = {b.x, b.y, b.z, b.w};
                #pragma unroll
                for (int i2 = 0; i2 < 4; ++i2)
                    #pragma unroll
                    for (int j = 0; j < 4; ++j)
                        acc[i2][q * 4 + j] += av[i2] * bv[j];
            }
        }
        __syncthreads();
    }
    #pragma unroll
    for (int i2 = 0; i2 < 4; ++i2)
        #pragma unroll
        for (int q = 0; q < 4; ++q) {
            float4 v = make_float4(acc[i2][q * 4 + 0], acc[i2][q * 4 + 1],
                                   acc[i2][q * 4 + 2], acc[i2][q * 4 + 3]);
            *(float4*)&MX[(size_t)(m0 + ty * 4 + i2) * Dd + q * 64 + tx * 4] = v;
        }
}

// ---- K1b: per-row mobius_matvec rescale + gamma; G bf16, g1 bf16 ----
__global__ __launch_bounds__(256) void k_gamma(const float* __restrict__ X,
                                               const float* __restrict__ MX,
                                               unsigned short* __restrict__ G,
                                               unsigned short* __restrict__ g1b) {
    __shared__ float red[8];
    int i = blockIdx.x, t = threadIdx.x;
    float x  = X[(size_t)i * Dd + t];
    float mx = MX[(size_t)i * Dd + t];
    float xn2  = blockReduceBcast(x * x, red);
    float mxn2 = blockReduceBcast(mx * mx, red);
    float xn  = fmaxf(sqrtf(xn2), 1e-15f);
    float mxn = fmaxf(sqrtf(mxn2), 1e-15f);
    float s = tanhf(mxn / xn * atanhf(clip1(xn))) / mxn;
    float xw = s * mx;
    float xw2 = blockReduceBcast(xw * xw, red);
    float gamma = 2.0f / fmaxf(1.0f - xw2, 1e-10f);
    G[(size_t)i * Dd + t] = f2bf(gamma * xw);
    if (t == 0) g1b[i] = f2bf(gamma - 1.0f);
}

// ---- K1c: Gt = transpose(G)  (bf16, 64x64 LDS tiles) ----
__global__ __launch_bounds__(256) void k_tr(const unsigned short* __restrict__ G,
                                            unsigned short* __restrict__ Gt) {
    __shared__ unsigned short Ts[64 * 66];
    int t = threadIdx.x;
    int i0 = blockIdx.x * 64;
    int j0 = blockIdx.y * 64;
    {
        int r = t >> 2, cq = t & 3;
        const uint4* src = (const uint4*)&G[(size_t)(i0 + r) * Dd + j0 + cq * 16];
        uint4 v0 = src[0], v1 = src[1];
        *(uint4*)&Ts[r * 66 + cq * 16]     = v0;
        *(uint4*)&Ts[r * 66 + cq * 16 + 8] = v1;
    }
    __syncthreads();
    {
        int c = t >> 2, rq = t & 3;
        unsigned short v[16];
        #pragma unroll
        for (int e = 0; e < 16; ++e) v[e] = Ts[(rq * 16 + e) * 66 + c];
        uint4 o0, o1;
        unsigned int* o = (unsigned int*)&o0;
        #pragma unroll
        for (int q = 0; q < 4; ++q)
            o[q] = (unsigned int)v[q * 2] | ((unsigned int)v[q * 2 + 1] << 16);
        o = (unsigned int*)&o1;
        #pragma unroll
        for (int q = 0; q < 4; ++q)
            o[q] = (unsigned int)v[8 + q * 2] | ((unsigned int)v[8 + q * 2 + 1] << 16);
        uint4* dst = (uint4*)&Gt[(size_t)(j0 + c) * Nn + i0 + rq * 16];
        dst[0] = o0; dst[1] = o1;
    }
}

// ======== K2 helpers ========
__device__ __forceinline__ void issue_batch(const float* __restrict__ A,
        const unsigned short* __restrict__ Gt,
        unsigned short (&Bsb)[256][64], float (&ab)[8],
        int m0, int kt0, int c0, int ar, int aq, int jrow, int kswz) {
    #pragma unroll
    for (int j = 0; j < 8; ++j) {
        const unsigned short* src = &Gt[(size_t)(c0 + j * 8 + jrow) * Nn + kt0 + kswz];
        __builtin_amdgcn_global_load_lds((const AS1 unsigned int*)src,
                                         (AS3 unsigned int*)&Bsb[c0 + j * 8][0],
                                         16, 0, 0);
    }
    const float* Ap = &A[(size_t)(m0 + ar) * Nn + kt0 + aq * 8];
    *(float4*)&ab[0] = *(const float4*)Ap;
    *(float4*)&ab[4] = *(const float4*)(Ap + 4);
}

__device__ __forceinline__ void cvt_fold(unsigned short (&Asb)[32][64],
        const unsigned short* g1s, const float (&ab)[8],
        int tile, int ar, int aq, float& dacc, float& racc) {
    vshort8 gv = *(const vshort8*)&g1s[tile * 64 + aq * 8];
    vshort8 o;
    #pragma unroll
    for (int e = 0; e < 8; ++e) {
        float av = ab[e];
        o[e] = (short)f2bf(av);
        float gf = __uint_as_float(((unsigned int)(unsigned short)gv[e]) << 16);
        dacc += av * gf;
        racc += av;
    }
    *(vshort8*)((char*)&Asb[ar][0] + ((aq * 16) ^ ((ar & 7) << 4))) = o;
}

__device__ __forceinline__ void mfma_step(const unsigned short (&Asb)[32][64],
        const unsigned short (&Bsb)[256][64],
        int l, int c0, vfloat4 (&acc)[2][4]) {
    #pragma unroll
    for (int kk = 0; kk < 64; kk += 32) {
        int ke2 = (kk + ((l >> 4) << 3)) * 2;
        vshort8 af[2], bfr[4];
        #pragma unroll
        for (int mi = 0; mi < 2; ++mi) {
            int row = mi * 16 + (l & 15);
            af[mi] = *(const vshort8*)((const char*)&Asb[row][0] + (ke2 ^ ((row & 7) << 4)));
        }
        #pragma unroll
        for (int ni = 0; ni < 4; ++ni) {
            int col = c0 + ni * 16 + (l & 15);
            bfr[ni] = *(const vshort8*)((const char*)&Bsb[col][0] + (ke2 ^ ((col & 7) << 4)));
        }
        #pragma unroll
        for (int mi = 0; mi < 2; ++mi)
            #pragma unroll
            for (int ni = 0; ni < 4; ++ni)
                acc[mi][ni] = __builtin_amdgcn_mfma_f32_16x16x32_bf16(
                    af[mi], bfr[ni], acc[mi][ni], 0, 0, 0);
    }
}

// ---- K2: P[split] = A(k-slice) @ G ; den/rs folded during A staging ----
// BM=32, BN=256, BK=64, split-K=2. B via global_load_lds (pre-swizzled source),
// raw s_barrier + counted vmcnt(10) (never 0 in the loop), 2-tile-deep prefetch.
__global__ __launch_bounds__(256, 2) void k_gemm1_mfma(
        const float* __restrict__ A,
        const unsigned short* __restrict__ Gt,
        const unsigned short* __restrict__ g1b,
        float* __restrict__ Ppart,
        float* __restrict__ denp,
        float* __restrict__ rsp) {
    __shared__ __align__(16) unsigned short Bs[2][256][64];  // 64 KB
    __shared__ __align__(16) unsigned short As[2][32][64];   // 8 KB
    __shared__ __align__(16) unsigned short g1s[4096];       // 8 KB

    const int t = threadIdx.x;
    const int l = t & 63, w = t >> 6;
    const int id = blockIdx.x;
    const int splt = id & 1;                 // XCD x (round-robin) sees one split
    const int m0 = (id >> 1) * 32;
    const int kb = splt * 4096;

    const int ar = t >> 3, aq = t & 7;       // A staging: row, k-octet
    const int c0 = w * 64;                   // wave's private 64 B-cols
    const int jrow = l >> 3;                 // gload_lds source decomposition
    const int kswz = ((l & 7) ^ jrow) << 3;  // pre-swizzle so linear LDS == XOR layout

    vfloat4 acc[2][4];
    #pragma unroll
    for (int mi = 0; mi < 2; ++mi)
        #pragma unroll
        for (int ni = 0; ni < 4; ++ni)
            acc[mi][ni] = (vfloat4){0.f, 0.f, 0.f, 0.f};
    float dacc = 0.f, racc = 0.f;
    float ab0[8], ab1[8];

    // ---- prologue: stage g1 slice, issue tiles 0 and 1 ----
    #pragma unroll
    for (int i = 0; i < 2; ++i) {
        int idx = i * 256 + t;
        uint4 gv = *(const uint4*)&g1b[kb + idx * 8];
        *(uint4*)&g1s[idx * 8] = gv;
    }
    issue_batch(A, Gt, Bs[0], ab0, m0, kb, c0, ar, aq, jrow, kswz);
    issue_batch(A, Gt, Bs[1], ab1, m0, kb + 64, c0, ar, aq, jrow, kswz);
    asm volatile("s_waitcnt vmcnt(10) lgkmcnt(0)" ::: "memory");
    __builtin_amdgcn_s_barrier();            // g1s + Bs[0] ready
    __builtin_amdgcn_sched_barrier(0);
    cvt_fold(As[0], g1s, ab0, 0, ar, aq, dacc, racc);
    asm volatile("s_waitcnt lgkmcnt(0)" ::: "memory");
    __builtin_amdgcn_s_barrier();            // As[0] visible
    __builtin_amdgcn_sched_barrier(0);

    // ---- main loop: 2 tiles per trip, literal buffer indices ----
    for (int tt = 0; tt < 32; ++tt) {
        int t0 = tt * 2;
        mfma_step(As[0], Bs[0], l, c0, acc);
        if (t0 < 62) {
            issue_batch(A, Gt, Bs[0], ab0, m0, kb + (t0 + 2) * 64, c0, ar, aq, jrow, kswz);
            asm volatile("s_waitcnt vmcnt(10)" ::: "memory");
        } else {
            asm volatile("s_waitcnt vmcnt(0)" ::: "memory");
        }
        cvt_fold(As[1], g1s, ab1, t0 + 1, ar, aq, dacc, racc);
        asm volatile("s_waitcnt lgkmcnt(0)" ::: "memory");
        __builtin_amdgcn_s_barrier();
        __builtin_amdgcn_sched_barrier(0);

        int t1 = t0 + 1;
        mfma_step(As[1], Bs[1], l, c0, acc);
        if (t1 < 62) {
            issue_batch(A, Gt, Bs[1], ab1, m0, kb + (t1 + 2) * 64, c0, ar, aq, jrow, kswz);
            asm volatile("s_waitcnt vmcnt(10)" ::: "memory");
        } else if (t1 == 62) {
            asm volatile("s_waitcnt vmcnt(0)" ::: "memory");
        }
        if (t1 < 63) {
            cvt_fold(As[0], g1s, ab0, t1 + 1, ar, aq, dacc, racc);
            asm volatile("s_waitcnt lgkmcnt(0)" ::: "memory");
        }
        __builtin_amdgcn_s_barrier();
        __builtin_amdgcn_sched_barrier(0);
    }

    // ---- den/rs: reduce across the 8 k-octet threads of each row ----
    dacc += __shfl_xor(dacc, 1); dacc += __shfl_xor(dacc, 2); dacc += __shfl_xor(dacc, 4);
    racc += __shfl_xor(racc, 1); racc += __shfl_xor(racc, 2); racc += __shfl_xor(racc, 4);
    if (aq == 0) {
        denp[splt * Nn + m0 + ar] = dacc;
        rsp[splt * Nn + m0 + ar] = racc;
    }

    // ---- store fp32 partial ----
    float* P = Ppart + (size_t)splt * ((size_t)Nn * Dd);
    #pragma unroll
    for (int mi = 0; mi < 2; ++mi)
        #pragma unroll
        for (int ni = 0; ni < 4; ++ni) {
            int row = m0 + mi * 16 + ((l >> 4) << 2);
            int col = c0 + ni * 16 + (l & 15);
            #pragma unroll
            for (int j = 0; j < 4; ++j)
                P[(size_t)(row + j) * Dd + col] = acc[mi][ni][j];
        }
}

// ---- K3: per-row gyromidpoint chain + H1 + hyperbolic logits ----
__global__ __launch_bounds__(256) void k_rowfix(const float* __restrict__ P0,
                                                const float* __restrict__ P1,
                                                const float* __restrict__ denp,
                                                const float* __restrict__ rsp,
                                                const float* __restrict__ Pk,
                                                const float* __restrict__ Wl,
                                                const float* __restrict__ kc,
                                                float* __restrict__ logits) {
    __shared__ float red[8];
    __shared__ float hs[256];
    __shared__ float PQ[16][2];
    int i = blockIdx.x, t = threadIdx.x;
    float nom = P0[(size_t)i * Dd + t] + P1[(size_t)i * Dd + t];
    float dv = denp[i] + denp[Nn + i];
    dv = (fabsf(dv) < 1e-10f) ? 1e-10f : dv;
    float tm = nom / dv;
    float r2 = blockReduceBcast(tm * tm, red);
    float r = fmaxf(sqrtf(r2), 1e-15f);
    float mmul = tanhf(0.5f * atanhf(clip1(r))) / r;
    float mj = mmul * tm;
    float mn2 = blockReduceBcast(mj * mj, red);
    float mn = fmaxf(sqrtf(mn2), 1e-15f);
    float sA = rsp[i] + rsp[Nn + i];
    float axmul = tanhf(sA * atanhf(clip1(mn))) / mn;
    float axw = axmul * mj;
    float yn2 = blockReduceBcast(axw * axw, red);
    float yn = fmaxf(sqrtf(yn2), 1e-15f);
    float v = atanhf(clip1(yn)) / yn * axw;
    float u = fmaxf(v, 0.0f);
    float un2 = blockReduceBcast(u * u, red);
    float un = fmaxf(sqrtf(un2), 1e-15f);
    float h = tanhf(un) / un * u;
    float h2 = blockReduceBcast(h * h, red);
    hs[t] = h;
    __syncthreads();
    int w = t >> 6, l = t & 63;
    #pragma unroll
    for (int kk = 0; kk < 4; ++kk) {
        int k = w * 4 + kk;
        float pp = 0.f, qq = 0.f;
        #pragma unroll
        for (int m = 0; m < 4; ++m) {
            float hv = hs[l + 64 * m];
            pp += hv * Pk[k * Dd + l + 64 * m];
            qq += hv * Wl[(l + 64 * m) * Cc + k];
        }
        pp = waveReduce(pp);
        qq = waveReduce(qq);
        if (l == 0) { PQ[k][0] = pp; PQ[k][1] = qq; }
    }
    __syncthreads();
    if (t < 16) {
        int k = t;
        float p2 = kc[k * 4 + 0], pw = kc[k * 4 + 1];
        float an = kc[k * 4 + 2], lam = kc[k * 4 + 3];
        float P = PQ[k][0], Q = PQ[k][1];
        float alpha = 1.0f - 2.0f * P + h2;
        float beta  = 1.0f - p2;
        float Dm = fmaxf(1.0f - 2.0f * P + p2 * h2, 1e-15f);
        float za  = (-alpha * pw + beta * Q) / Dm;
        float zn2 = (alpha * alpha * p2 - 2.0f * alpha * beta * P + beta * beta * h2)
                    / (Dm * Dm);
        float dd = fmaxf(1.0f - zn2, 1e-10f) * an;
        float dist = asinhf(2.0f * za / dd);
        logits[(size_t)i * Cc + k] = lam * an * dist;
    }
}

// ---- K4: partials of out = A @ logits (j-split x16) ----
__global__ __launch_bounds__(256) void k_gemm2(const float* __restrict__ A,
                                               const float* __restrict__ L,
                                               float* __restrict__ part) {
    __shared__ __align__(16) float Ls[64 * 20];
    __shared__ float Pacc[256 * 16];
    int t = threadIdx.x;
    int r0 = blockIdx.x * 256;
    int jbase = blockIdx.y * 512;
    int q = t & 3, g = t >> 2;
    float acc[4][16] = {};
    for (int jc = 0; jc < 512; jc += 64) {
        {
            int jrow = t >> 2, kq = t & 3;
            *(float4*)&Ls[jrow * 20 + kq * 4] =
                *(const float4*)&L[(size_t)(jbase + jc + jrow) * Cc + kq * 4];
        }
        __syncthreads();
        #pragma unroll
        for (int m = 0; m < 4; ++m) {
            int jl = m * 16 + q * 4;
            float av[4][4];
            #pragma unroll
            for (int rr = 0; rr < 4; ++rr) {
                float4 tmp = *(const float4*)&A[(size_t)(r0 + g * 4 + rr) * Nn
                                                + jbase + jc + jl];
                av[rr][0] = tmp.x; av[rr][1] = tmp.y;
                av[rr][2] = tmp.z; av[rr][3] = tmp.w;
            }
            #pragma unroll
            for (int jj = 0; jj < 4; ++jj) {
                const float* lr = &Ls[(jl + jj) * 20];
                float lv[16];
                #pragma unroll
                for (int k2 = 0; k2 < 16; k2 += 4) {
                    float4 lt = *(const float4*)&lr[k2];
                    lv[k2] = lt.x; lv[k2 + 1] = lt.y;
                    lv[k2 + 2] = lt.z; lv[k2 + 3] = lt.w;
                }
                #pragma unroll
                for (int rr = 0; rr < 4; ++rr)
                    #pragma unroll
                    for (int k2 = 0; k2 < 16; ++k2)
                        acc[rr][k2] += av[rr][jj] * lv[k2];
            }
        }
        __syncthreads();
    }
    for (int ii = t; ii < 4096; ii += 256) Pacc[ii] = 0.f;
    __syncthreads();
    for (int qq = 0; qq < 4; ++qq) {
        if (q == qq) {
            #pragma unroll
            for (int rr = 0; rr < 4; ++rr)
                #pragma unroll
                for (int k2 = 0; k2 < 16; ++k2)
                    Pacc[(g * 4 + rr) * 16 + k2] += acc[rr][k2];
        }
        __syncthreads();
    }
    float* dst = &part[(size_t)blockIdx.y * (Nn * Cc) + (size_t)r0 * Cc];
    for (int ii = t * 4; ii < 4096; ii += 1024)
        *(float4*)&dst[ii] = *(const float4*)&Pacc[ii];
}

// ---- K5: reduce j-split partials ----
__global__ __launch_bounds__(256) void k_reduce(const float* __restrict__ part,
                                                float* __restrict__ out) {
    int i = blockIdx.x * 256 + threadIdx.x;
    float s = 0.f;
    #pragma unroll
    for (int j = 0; j < 16; ++j) s += part[(size_t)j * (Nn * Cc) + i];
    out[i] = s;
}

extern "C" void kernel_launch(void* const* d_in, const int* in_sizes, int n_in,
                              void* d_out, int out_size, void* d_ws, size_t ws_size,
                              hipStream_t stream) {
    const float* X  = (const float*)d_in[0];
    const float* A  = (const float*)d_in[1];
    const float* W  = (const float*)d_in[2];
    const float* Wl = (const float*)d_in[3];
    const float* Pk = (const float*)d_in[4];
    float* out = (float*)d_out;
    float* ws = (float*)d_ws;
    if (ws_size < (size_t)WS_FLOATS * sizeof(float)) return;

    float* P0 = ws + OFF_P0;
    float* P1 = ws + OFF_P1;
    unsigned short* G   = (unsigned short*)(ws + OFF_G);
    unsigned short* Gt  = (unsigned short*)(ws + OFF_GT);
    unsigned short* g1b = (unsigned short*)(ws + OFF_G1B);
    float* lg   = ws + OFF_G;                      // logits reuse G region
    float* denp = ws + OFF_DEN;
    float* rsp  = ws + OFF_RS;
    float* kc   = ws + OFF_KC;

    k_consts<<<16, 256, 0, stream>>>(Wl, Pk, kc);
    k_xwt<<<128, 256, 0, stream>>>(X, W, P0 /*MX*/);
    k_gamma<<<Nn, 256, 0, stream>>>(X, P0 /*MX*/, G, g1b);
    k_tr<<<dim3(128, 4), 256, 0, stream>>>(G, Gt);
    k_gemm1_mfma<<<512, 256, 0, stream>>>(A, Gt, g1b, P0, denp, rsp);
    k_rowfix<<<Nn, 256, 0, stream>>>(P0, P1, denp, rsp, Pk, Wl, kc, lg);
    k_gemm2<<<dim3(32, 16), 256, 0, stream>>>(A, lg, P0);
    k_reduce<<<512, 256, 0, stream>>>(P0, out);
}